// Round 2
// baseline (175.993 us; speedup 1.0000x reference)
//
#include <hip/hip_runtime.h>
#include <hip/hip_bf16.h>

typedef __bf16 bf16;
typedef __bf16 bf16x8 __attribute__((ext_vector_type(8)));
typedef __bf16 bf16x4 __attribute__((ext_vector_type(4)));
typedef float  f32x4  __attribute__((ext_vector_type(4)));

#define NB    2
#define CCH   256
#define NPIX  2304
#define WIMG  48
// scale * log2(e) = (1/sqrt(32)) * 1.4426950408889634
#define SLOG2E 0.25503487f

// ---------------------------------------------------------------------------
// Kernel 1: qkv = w_qkv @ x   (M=768, K=256, cols = B*2304)
// Writes Qt/Kt as [bh][n][32] bf16 (token-major), V as [bh][32][n] bf16.
// ---------------------------------------------------------------------------
__global__ __launch_bounds__(256) void qkv_gemm(const float* __restrict__ x,
                                                const float* __restrict__ w,
                                                bf16* __restrict__ Qt,
                                                bf16* __restrict__ Kt,
                                                bf16* __restrict__ Vb) {
    __shared__ __align__(16) bf16 xT[64][40];   // [n][c] transposed tile, padded
    const int tid  = threadIdx.x;
    const int lane = tid & 63;
    const int wv   = tid >> 6;
    const int wn   = wv & 1, wo = wv >> 1;
    const int l15  = lane & 15, l4 = lane >> 4;
    const int g0 = blockIdx.x * 64;
    const int b  = g0 / NPIX;
    const int n0 = g0 % NPIX;
    const int o0 = blockIdx.y * 64;
    const float* xb = x + (size_t)b * CCH * NPIX;

    f32x4 acc[2][2] = {};

    for (int kc = 0; kc < 8; ++kc) {
        const int c0 = kc * 32;
        // stage x^T tile: 32 channels x 64 cols
        for (int r = 0; r < 8; ++r) {
            int idx = r * 256 + tid;
            int c = idx >> 6, n = idx & 63;
            xT[n][c] = (bf16)xb[(size_t)(c0 + c) * NPIX + n0 + n];
        }
        __syncthreads();
        bf16x8 afr[2], bfr[2];
        for (int at = 0; at < 2; ++at) {
            const float* wp = w + (size_t)(o0 + wo * 32 + at * 16 + l15) * CCH + c0 + l4 * 8;
            f32x4 w0 = *(const f32x4*)wp;
            f32x4 w1 = *(const f32x4*)(wp + 4);
            bf16x8 a;
            for (int i = 0; i < 4; ++i) { a[i] = (bf16)w0[i]; a[i + 4] = (bf16)w1[i]; }
            afr[at] = a;
        }
        for (int bt = 0; bt < 2; ++bt)
            bfr[bt] = *(const bf16x8*)&xT[wn * 32 + bt * 16 + l15][l4 * 8];
        for (int at = 0; at < 2; ++at)
            for (int bt = 0; bt < 2; ++bt)
                acc[at][bt] = __builtin_amdgcn_mfma_f32_16x16x32_bf16(afr[at], bfr[bt],
                                                                     acc[at][bt], 0, 0, 0);
        __syncthreads();
    }

    // epilogue: route 16-row tiles to q/k/v buffers
    for (int at = 0; at < 2; ++at) {
        const int otile = o0 + wo * 32 + at * 16;      // 16-aligned, never crosses 32-bdry
        const int h    = otile / 96;
        const int role = (otile % 96) / 32;            // 0=q 1=k 2=v
        const int ddb  = (otile % 32) + l4 * 4;        // dd for reg r is ddb + r
        const int bh   = b * 8 + h;
        for (int bt = 0; bt < 2; ++bt) {
            const int n = n0 + wn * 32 + bt * 16 + l15;
            if (role == 2) {
                for (int r = 0; r < 4; ++r)
                    Vb[(size_t)(bh * 32 + ddb + r) * NPIX + n] = (bf16)acc[at][bt][r];
            } else {
                bf16x4 pk;
                for (int r = 0; r < 4; ++r) pk[r] = (bf16)acc[at][bt][r];
                bf16* dst = (role == 0) ? Qt : Kt;
                *(bf16x4*)&dst[((size_t)bh * NPIX + n) * 32 + ddb] = pk;
            }
        }
    }
}

// ---------------------------------------------------------------------------
// Kernel 2: flash attention over keys. Grid (36 q-tiles, 16 bh), 4 waves.
// Each wave owns 16 query columns; all waves share K/V tiles (Tk=64).
// ---------------------------------------------------------------------------
__global__ __launch_bounds__(256) void attn_kernel(const bf16* __restrict__ Qt,
                                                   const bf16* __restrict__ Kt,
                                                   const bf16* __restrict__ Vb,
                                                   bf16* __restrict__ aout) {
    __shared__ __align__(16) bf16 Ktile[64][40];   // [k][d]  padded (80B rows)
    __shared__ __align__(16) bf16 Vtile[32][72];   // [d][k]  padded (144B rows)
    __shared__ __align__(16) bf16 Ptile[64][72];   // [q][k]  per-wave-private rows
    const int tid  = threadIdx.x;
    const int lane = tid & 63;
    const int wv   = tid >> 6;
    const int l15  = lane & 15, l4 = lane >> 4;
    const int bh = blockIdx.y;
    const int q0 = blockIdx.x * 64;
    const int q  = q0 + wv * 16 + l15;

    const bf16* Kbh = Kt + (size_t)bh * NPIX * 32;
    const bf16* Vbh = Vb + (size_t)bh * 32 * NPIX;

    // Q fragment: B[k=d][col=q], lane holds d = l4*8..+7 for its q column
    bf16x8 qf = *(const bf16x8*)&Qt[((size_t)bh * NPIX + q) * 32 + l4 * 8];

    f32x4 O0 = {}, O1 = {};
    float m_run = -INFINITY, l_run = 0.f;

    for (int kt = 0; kt < 36; ++kt) {
        const int k0 = kt * 64;
        {   // stage K tile (linear-ish copy) and V tile
            int kk = tid >> 2, j = tid & 3;
            *(bf16x8*)&Ktile[kk][j * 8] =
                *(const bf16x8*)&Kbh[(size_t)(k0 + kk) * 32 + j * 8];
            int dd = tid >> 3, jv = tid & 7;
            *(bf16x8*)&Vtile[dd][jv * 8] =
                *(const bf16x8*)&Vbh[(size_t)dd * NPIX + k0 + jv * 8];
        }
        __syncthreads();

        // S = K^T Q  (A = K-tile rows, B = Q frag). s[rt] covers k-rows rt*16..+15
        f32x4 s[4];
        for (int rt = 0; rt < 4; ++rt) {
            bf16x8 a = *(const bf16x8*)&Ktile[rt * 16 + l15][l4 * 8];
            f32x4 z = {};
            s[rt] = __builtin_amdgcn_mfma_f32_16x16x32_bf16(a, qf, z, 0, 0, 0);
        }

        // online softmax over the key dim (per q column = lanes {l, l^16, l^32, l^48})
        float tmax = -INFINITY;
        for (int rt = 0; rt < 4; ++rt)
            for (int r = 0; r < 4; ++r) {
                float e = s[rt][r] * SLOG2E;
                s[rt][r] = e;
                tmax = fmaxf(tmax, e);
            }
        tmax = fmaxf(tmax, __shfl_xor(tmax, 16));
        tmax = fmaxf(tmax, __shfl_xor(tmax, 32));
        const float m_new = fmaxf(m_run, tmax);
        const float f = __builtin_amdgcn_exp2f(m_run - m_new);
        float psum = 0.f;
        for (int rt = 0; rt < 4; ++rt)
            for (int r = 0; r < 4; ++r) {
                float p = __builtin_amdgcn_exp2f(s[rt][r] - m_new);
                s[rt][r] = p;
                psum += p;
            }
        psum += __shfl_xor(psum, 16);
        psum += __shfl_xor(psum, 32);
        l_run = l_run * f + psum;
        m_run = m_new;
        for (int i = 0; i < 4; ++i) { O0[i] *= f; O1[i] *= f; }

        // P -> LDS ([q][k] so PV B-frags are contiguous); rows are wave-private
        const int qrow = wv * 16 + l15;
        for (int rt = 0; rt < 4; ++rt) {
            bf16x4 pk;
            for (int r = 0; r < 4; ++r) pk[r] = (bf16)s[rt][r];
            *(bf16x4*)&Ptile[qrow][rt * 16 + l4 * 4] = pk;
        }

        // O += V * P   (A = V rows d, B = P columns q), K split 2x32
        for (int ks = 0; ks < 2; ++ks) {
            bf16x8 pb = *(const bf16x8*)&Ptile[qrow][ks * 32 + l4 * 8];
            bf16x8 v0 = *(const bf16x8*)&Vtile[l15][ks * 32 + l4 * 8];
            bf16x8 v1 = *(const bf16x8*)&Vtile[16 + l15][ks * 32 + l4 * 8];
            O0 = __builtin_amdgcn_mfma_f32_16x16x32_bf16(v0, pb, O0, 0, 0, 0);
            O1 = __builtin_amdgcn_mfma_f32_16x16x32_bf16(v1, pb, O1, 0, 0, 0);
        }
        __syncthreads();
    }

    const float inv = 1.f / l_run;
    const int b = bh >> 3, h = bh & 7;
    for (int dt = 0; dt < 2; ++dt) {
        f32x4 O = dt ? O1 : O0;
        for (int r = 0; r < 4; ++r) {
            int d = dt * 16 + l4 * 4 + r;
            aout[(size_t)(b * 256 + h * 32 + d) * NPIX + q] = (bf16)(O[r] * inv);
        }
    }
}

// ---------------------------------------------------------------------------
// Kernel 3: lepe = depthwise 3x3 conv(v) + bias, added into attention output
// ---------------------------------------------------------------------------
__global__ __launch_bounds__(256) void lepe_kernel(const bf16* __restrict__ Vb,
                                                   const float* __restrict__ wl,
                                                   const float* __restrict__ bl,
                                                   bf16* __restrict__ aout) {
    __shared__ float vp[WIMG * WIMG];
    const int bc = blockIdx.x;           // b*256 + c  (V layout == [B,C,N])
    const int c  = bc & 255;
    const bf16* src = Vb + (size_t)bc * NPIX;
    bf16* dst = aout + (size_t)bc * NPIX;
    const int tid = threadIdx.x;
    for (int r = 0; r < 9; ++r) vp[r * 256 + tid] = (float)src[r * 256 + tid];
    __syncthreads();
    float wgt[9];
    for (int i = 0; i < 9; ++i) wgt[i] = wl[c * 9 + i];
    const float bias = bl[c];
    for (int r = 0; r < 9; ++r) {
        const int idx = r * 256 + tid;
        const int y = idx / WIMG, xx = idx % WIMG;
        float acc = bias;
        for (int dy = 0; dy < 3; ++dy) {
            const int yy = y + dy - 1;
            if (yy < 0 || yy >= WIMG) continue;
            for (int dx = 0; dx < 3; ++dx) {
                const int xc = xx + dx - 1;
                if (xc < 0 || xc >= WIMG) continue;
                acc += vp[yy * WIMG + xc] * wgt[dy * 3 + dx];
            }
        }
        dst[idx] = (bf16)((float)dst[idx] + acc);
    }
}

// ---------------------------------------------------------------------------
// Kernel 4: out = w_proj @ attn_out + b_proj  (fp32 output)
// ---------------------------------------------------------------------------
__global__ __launch_bounds__(256) void proj_gemm(const bf16* __restrict__ ain,
                                                 const float* __restrict__ w,
                                                 const float* __restrict__ bp,
                                                 float* __restrict__ out) {
    __shared__ __align__(16) bf16 aT[64][40];
    const int tid  = threadIdx.x;
    const int lane = tid & 63;
    const int wv   = tid >> 6;
    const int wn   = wv & 1, wo = wv >> 1;
    const int l15  = lane & 15, l4 = lane >> 4;
    const int g0 = blockIdx.x * 64;
    const int b  = g0 / NPIX;
    const int n0 = g0 % NPIX;
    const int o0 = blockIdx.y * 64;
    const bf16* ab = ain + (size_t)b * CCH * NPIX;

    f32x4 acc[2][2] = {};
    for (int kc = 0; kc < 8; ++kc) {
        const int c0 = kc * 32;
        for (int r = 0; r < 8; ++r) {
            int idx = r * 256 + tid;
            int ci = idx >> 6, n = idx & 63;
            aT[n][ci] = ab[(size_t)(c0 + ci) * NPIX + n0 + n];
        }
        __syncthreads();
        bf16x8 afr[2], bfr[2];
        for (int at = 0; at < 2; ++at) {
            const float* wp = w + (size_t)(o0 + wo * 32 + at * 16 + l15) * CCH + c0 + l4 * 8;
            f32x4 w0 = *(const f32x4*)wp;
            f32x4 w1 = *(const f32x4*)(wp + 4);
            bf16x8 a;
            for (int i = 0; i < 4; ++i) { a[i] = (bf16)w0[i]; a[i + 4] = (bf16)w1[i]; }
            afr[at] = a;
        }
        for (int bt = 0; bt < 2; ++bt)
            bfr[bt] = *(const bf16x8*)&aT[wn * 32 + bt * 16 + l15][l4 * 8];
        for (int at = 0; at < 2; ++at)
            for (int bt = 0; bt < 2; ++bt)
                acc[at][bt] = __builtin_amdgcn_mfma_f32_16x16x32_bf16(afr[at], bfr[bt],
                                                                     acc[at][bt], 0, 0, 0);
        __syncthreads();
    }
    for (int at = 0; at < 2; ++at)
        for (int bt = 0; bt < 2; ++bt) {
            const int n = n0 + wn * 32 + bt * 16 + l15;
            for (int r = 0; r < 4; ++r) {
                const int o = o0 + wo * 32 + at * 16 + l4 * 4 + r;
                out[(size_t)(b * 256 + o) * NPIX + n] = acc[at][bt][r] + bp[o];
            }
        }
}

// ---------------------------------------------------------------------------
extern "C" void kernel_launch(void* const* d_in, const int* in_sizes, int n_in,
                              void* d_out, int out_size, void* d_ws, size_t ws_size,
                              hipStream_t stream) {
    const float* x      = (const float*)d_in[0];
    const float* w_qkv  = (const float*)d_in[1];
    const float* w_lepe = (const float*)d_in[2];
    const float* b_lepe = (const float*)d_in[3];
    const float* w_proj = (const float*)d_in[4];
    const float* b_proj = (const float*)d_in[5];
    float* out = (float*)d_out;

    // workspace layout (bf16 elements): Qt | Kt | V | attn_out, each 16*2304*32
    bf16* Qt   = (bf16*)d_ws;
    bf16* Kt   = Qt + 1179648;
    bf16* Vb   = Kt + 1179648;
    bf16* aout = Vb + 1179648;

    qkv_gemm  <<<dim3(72, 12), 256, 0, stream>>>(x, w_qkv, Qt, Kt, Vb);
    attn_kernel<<<dim3(36, 16), 256, 0, stream>>>(Qt, Kt, Vb, aout);
    lepe_kernel<<<dim3(512),    256, 0, stream>>>(Vb, w_lepe, b_lepe, aout);
    proj_gemm <<<dim3(72, 4),   256, 0, stream>>>(aout, w_proj, b_proj, out);
}

// Round 5
// 161.069 us; speedup vs baseline: 1.0927x; 1.0927x over previous
//
#include <hip/hip_runtime.h>
#include <hip/hip_bf16.h>

typedef __bf16 bf16;
typedef __bf16 bf16x8 __attribute__((ext_vector_type(8)));
typedef __bf16 bf16x4 __attribute__((ext_vector_type(4)));
typedef float  f32x4  __attribute__((ext_vector_type(4)));
typedef float  f32x2  __attribute__((ext_vector_type(2)));

#define NB    2
#define CCH   256
#define NPIX  2304
#define WIMG  48
// scale * log2(e) = (1/sqrt(32)) * 1.4426950408889634  (folded into Kt)
#define SLOG2E 0.25503487f
#define NSPLIT 2
#define KHALF  1152
#define TK     128
#define NITER  9

// ---------------------------------------------------------------------------
// Kernel 1: qkv = w_qkv @ x   (M=768, K=256, cols = B*2304)
// Qt/Kt as [bh][n][32] bf16 (token-major; Kt pre-scaled by scale*log2e),
// V as [bh][32][n] bf16.
// ---------------------------------------------------------------------------
__global__ __launch_bounds__(256) void qkv_gemm(const float* __restrict__ x,
                                                const float* __restrict__ w,
                                                bf16* __restrict__ Qt,
                                                bf16* __restrict__ Kt,
                                                bf16* __restrict__ Vb) {
    __shared__ __align__(16) bf16 xT[64][40];   // [n][c] transposed tile, padded
    const int tid  = threadIdx.x;
    const int lane = tid & 63;
    const int wv   = tid >> 6;
    const int wn   = wv & 1, wo = wv >> 1;
    const int l15  = lane & 15, l4 = lane >> 4;
    const int g0 = blockIdx.x * 64;
    const int b  = g0 / NPIX;
    const int n0 = g0 % NPIX;
    const int o0 = blockIdx.y * 64;
    const float* xb = x + (size_t)b * CCH * NPIX;

    f32x4 acc[2][2] = {};

    for (int kc = 0; kc < 8; ++kc) {
        const int c0 = kc * 32;
        for (int r = 0; r < 8; ++r) {
            int idx = r * 256 + tid;
            int c = idx >> 6, n = idx & 63;
            xT[n][c] = (bf16)xb[(size_t)(c0 + c) * NPIX + n0 + n];
        }
        __syncthreads();
        bf16x8 afr[2], bfr[2];
        for (int at = 0; at < 2; ++at) {
            const float* wp = w + (size_t)(o0 + wo * 32 + at * 16 + l15) * CCH + c0 + l4 * 8;
            f32x4 w0 = *(const f32x4*)wp;
            f32x4 w1 = *(const f32x4*)(wp + 4);
            bf16x8 a;
            for (int i = 0; i < 4; ++i) { a[i] = (bf16)w0[i]; a[i + 4] = (bf16)w1[i]; }
            afr[at] = a;
        }
        for (int bt = 0; bt < 2; ++bt)
            bfr[bt] = *(const bf16x8*)&xT[wn * 32 + bt * 16 + l15][l4 * 8];
        for (int at = 0; at < 2; ++at)
            for (int bt = 0; bt < 2; ++bt)
                acc[at][bt] = __builtin_amdgcn_mfma_f32_16x16x32_bf16(afr[at], bfr[bt],
                                                                     acc[at][bt], 0, 0, 0);
        __syncthreads();
    }

    for (int at = 0; at < 2; ++at) {
        const int otile = o0 + wo * 32 + at * 16;
        const int h    = otile / 96;
        const int role = (otile % 96) / 32;            // 0=q 1=k 2=v
        const int ddb  = (otile % 32) + l4 * 4;
        const int bh   = b * 8 + h;
        for (int bt = 0; bt < 2; ++bt) {
            const int n = n0 + wn * 32 + bt * 16 + l15;
            if (role == 2) {
                for (int r = 0; r < 4; ++r)
                    Vb[(size_t)(bh * 32 + ddb + r) * NPIX + n] = (bf16)acc[at][bt][r];
            } else if (role == 1) {
                bf16x4 pk;
                for (int r = 0; r < 4; ++r) pk[r] = (bf16)(acc[at][bt][r] * SLOG2E);
                *(bf16x4*)&Kt[((size_t)bh * NPIX + n) * 32 + ddb] = pk;
            } else {
                bf16x4 pk;
                for (int r = 0; r < 4; ++r) pk[r] = (bf16)acc[at][bt][r];
                *(bf16x4*)&Qt[((size_t)bh * NPIX + n) * 32 + ddb] = pk;
            }
        }
    }
}

// ---------------------------------------------------------------------------
// Kernel 2: flash attention, K-split x2 (flash-decoding). Grid (36, 16, 2).
// Tk=128, 9 iters/block, reg-prefetch double-buffered staging (async-STAGE).
// Writes unnormalized O + (m,l) partials (fp32) for the combine pass.
// ---------------------------------------------------------------------------
__global__ __launch_bounds__(256, 4) void attn_kernel(const bf16* __restrict__ Qt,
                                                      const bf16* __restrict__ Kt,
                                                      const bf16* __restrict__ Vb,
                                                      float* __restrict__ Opart,
                                                      float* __restrict__ MLpart) {
    __shared__ __align__(16) bf16 Ktile[128][40];   // [k][d]   80B rows
    __shared__ __align__(16) bf16 Vtile[32][136];   // [d][k]   272B rows
    __shared__ __align__(16) bf16 Ptile[64][136];   // [q][k]   wave-private rows
    const int tid  = threadIdx.x;
    const int lane = tid & 63;
    const int wv   = tid >> 6;
    const int l15  = lane & 15, l4 = lane >> 4;
    const int bh    = blockIdx.y;
    const int split = blockIdx.z;
    const int q0 = blockIdx.x * 64;
    const int q  = q0 + wv * 16 + l15;

    const bf16* Kbh = Kt + (size_t)bh * NPIX * 32 + (size_t)split * KHALF * 32;
    const bf16* Vbh = Vb + (size_t)bh * 32 * NPIX + split * KHALF;

    // Q fragment: B[k=d][col=q], lane holds d = l4*8..+7 for its q column
    bf16x8 qf = *(const bf16x8*)&Qt[((size_t)bh * NPIX + q) * 32 + l4 * 8];

    // staging decomposition (same lanes load & store: global->reg->LDS)
    const int krow = tid >> 1, kcol = (tid & 1) * 16;
    const int vd   = tid >> 3, vc   = (tid & 7) * 16;
    const bf16* ksrc = Kbh + (size_t)krow * 32 + kcol;
    const bf16* vsrc = Vbh + (size_t)vd * NPIX + vc;

    bf16x8 ka, kb, va, vb_;
    ka  = *(const bf16x8*)(ksrc);
    kb  = *(const bf16x8*)(ksrc + 8);
    va  = *(const bf16x8*)(vsrc);
    vb_ = *(const bf16x8*)(vsrc + 8);
    *(bf16x8*)&Ktile[krow][kcol]     = ka;
    *(bf16x8*)&Ktile[krow][kcol + 8] = kb;
    *(bf16x8*)&Vtile[vd][vc]         = va;
    *(bf16x8*)&Vtile[vd][vc + 8]     = vb_;
    __syncthreads();

    f32x4 O0 = {}, O1 = {};
    float m_run = -INFINITY, l_run = 0.f;
    const int qrow = wv * 16 + l15;

    for (int kt = 0; kt < NITER; ++kt) {
        if (kt + 1 < NITER) {   // issue next-tile loads early (hidden under compute)
            const bf16* ks = ksrc + (size_t)(kt + 1) * TK * 32;
            const bf16* vs = vsrc + (kt + 1) * TK;
            ka  = *(const bf16x8*)(ks);
            kb  = *(const bf16x8*)(ks + 8);
            va  = *(const bf16x8*)(vs);
            vb_ = *(const bf16x8*)(vs + 8);
        }

        // S = K^T Q (K pre-scaled by scale*log2e). s[rt] = k-rows rt*16..+15
        f32x4 s[8];
        for (int rt = 0; rt < 8; ++rt) {
            bf16x8 a = *(const bf16x8*)&Ktile[rt * 16 + l15][l4 * 8];
            f32x4 z = {};
            s[rt] = __builtin_amdgcn_mfma_f32_16x16x32_bf16(a, qf, z, 0, 0, 0);
        }

        // online softmax over key dim (column q = lanes {l, l^16, l^32, l^48})
        float tmax = -INFINITY;
        for (int rt = 0; rt < 8; ++rt)
            for (int r = 0; r < 4; ++r) tmax = fmaxf(tmax, s[rt][r]);
        tmax = fmaxf(tmax, __shfl_xor(tmax, 16));
        tmax = fmaxf(tmax, __shfl_xor(tmax, 32));
        const float m_new = fmaxf(m_run, tmax);
        const float f = __builtin_amdgcn_exp2f(m_run - m_new);
        float psum = 0.f;
        for (int rt = 0; rt < 8; ++rt) {
            bf16x4 pk;
            for (int r = 0; r < 4; ++r) {
                float p = __builtin_amdgcn_exp2f(s[rt][r] - m_new);
                psum += p;
                pk[r] = (bf16)p;
            }
            *(bf16x4*)&Ptile[qrow][rt * 16 + l4 * 4] = pk;
        }
        psum += __shfl_xor(psum, 16);
        psum += __shfl_xor(psum, 32);
        l_run = l_run * f + psum;
        m_run = m_new;
        for (int i = 0; i < 4; ++i) { O0[i] *= f; O1[i] *= f; }

        // O += V * P  (A = V rows d, B = P cols q); 4 k-chunks of 32
        for (int ks = 0; ks < 4; ++ks) {
            bf16x8 pb = *(const bf16x8*)&Ptile[qrow][ks * 32 + l4 * 8];
            bf16x8 v0 = *(const bf16x8*)&Vtile[l15][ks * 32 + l4 * 8];
            bf16x8 v1 = *(const bf16x8*)&Vtile[16 + l15][ks * 32 + l4 * 8];
            O0 = __builtin_amdgcn_mfma_f32_16x16x32_bf16(v0, pb, O0, 0, 0, 0);
            O1 = __builtin_amdgcn_mfma_f32_16x16x32_bf16(v1, pb, O1, 0, 0, 0);
        }
        __syncthreads();               // all waves done reading tile kt
        if (kt + 1 < NITER) {          // commit prefetched tile kt+1
            *(bf16x8*)&Ktile[krow][kcol]     = ka;
            *(bf16x8*)&Ktile[krow][kcol + 8] = kb;
            *(bf16x8*)&Vtile[vd][vc]         = va;
            *(bf16x8*)&Vtile[vd][vc + 8]     = vb_;
        }
        __syncthreads();               // tile kt+1 visible
    }

    // store unnormalized partials
    f32x4* Op4 = (f32x4*)(Opart + ((size_t)(split * 16 + bh) * NPIX + q) * 32);
    Op4[l4]     = O0;   // d = l4*4 + r
    Op4[4 + l4] = O1;   // d = 16 + l4*4 + r
    if (l4 == 0) {
        f32x2 ml; ml[0] = m_run; ml[1] = l_run;
        *(f32x2*)&MLpart[((size_t)(split * 16 + bh) * NPIX + q) * 2] = ml;
    }
}

// ---------------------------------------------------------------------------
// Kernel 2b: combine the two K-split partials -> aout bf16 [bh*32+d][q]
// ---------------------------------------------------------------------------
__global__ __launch_bounds__(256) void combine_kernel(const float* __restrict__ Opart,
                                                      const float* __restrict__ MLpart,
                                                      bf16* __restrict__ aout) {
    const int tid = threadIdx.x;
    const int qq = tid & 63, dg = tid >> 6;     // dg: 8 d's per thread
    const int bh = blockIdx.y;
    const int q  = blockIdx.x * 64 + qq;
    f32x2 ml0 = *(const f32x2*)&MLpart[((size_t)bh * NPIX + q) * 2];
    f32x2 ml1 = *(const f32x2*)&MLpart[((size_t)(16 + bh) * NPIX + q) * 2];
    const float m  = fmaxf(ml0[0], ml1[0]);
    const float w0 = __builtin_amdgcn_exp2f(ml0[0] - m);
    const float w1 = __builtin_amdgcn_exp2f(ml1[0] - m);
    const float inv = 1.f / (w0 * ml0[1] + w1 * ml1[1]);
    const f32x4* p0 = (const f32x4*)&Opart[((size_t)bh * NPIX + q) * 32 + dg * 8];
    const f32x4* p1 = (const f32x4*)&Opart[((size_t)(16 + bh) * NPIX + q) * 32 + dg * 8];
    f32x4 a0 = p0[0], b0 = p0[1], a1 = p1[0], b1 = p1[1];
    for (int j = 0; j < 4; ++j) {
        a0[j] = (w0 * a0[j] + w1 * a1[j]) * inv;
        b0[j] = (w0 * b0[j] + w1 * b1[j]) * inv;
    }
    for (int j = 0; j < 4; ++j) {
        aout[(size_t)(bh * 32 + dg * 8 + j)     * NPIX + q] = (bf16)a0[j];
        aout[(size_t)(bh * 32 + dg * 8 + 4 + j) * NPIX + q] = (bf16)b0[j];
    }
}

// ---------------------------------------------------------------------------
// Kernel 3: lepe = depthwise 3x3 conv(v) + bias, added into attention output
// ---------------------------------------------------------------------------
__global__ __launch_bounds__(256) void lepe_kernel(const bf16* __restrict__ Vb,
                                                   const float* __restrict__ wl,
                                                   const float* __restrict__ bl,
                                                   bf16* __restrict__ aout) {
    __shared__ float vp[WIMG * WIMG];
    const int bc = blockIdx.x;           // b*256 + c  (V layout == [B,C,N])
    const int c  = bc & 255;
    const bf16* src = Vb + (size_t)bc * NPIX;
    bf16* dst = aout + (size_t)bc * NPIX;
    const int tid = threadIdx.x;
    for (int r = 0; r < 9; ++r) vp[r * 256 + tid] = (float)src[r * 256 + tid];
    __syncthreads();
    float wgt[9];
    for (int i = 0; i < 9; ++i) wgt[i] = wl[c * 9 + i];
    const float bias = bl[c];
    for (int r = 0; r < 9; ++r) {
        const int idx = r * 256 + tid;
        const int y = idx / WIMG, xx = idx % WIMG;
        float acc = bias;
        for (int dy = 0; dy < 3; ++dy) {
            const int yy = y + dy - 1;
            if (yy < 0 || yy >= WIMG) continue;
            for (int dx = 0; dx < 3; ++dx) {
                const int xc = xx + dx - 1;
                if (xc < 0 || xc >= WIMG) continue;
                acc += vp[yy * WIMG + xc] * wgt[dy * 3 + dx];
            }
        }
        dst[idx] = (bf16)((float)dst[idx] + acc);
    }
}

// ---------------------------------------------------------------------------
// Kernel 4: out = w_proj @ attn_out + b_proj  (fp32 output)
// ---------------------------------------------------------------------------
__global__ __launch_bounds__(256) void proj_gemm(const bf16* __restrict__ ain,
                                                 const float* __restrict__ w,
                                                 const float* __restrict__ bp,
                                                 float* __restrict__ out) {
    __shared__ __align__(16) bf16 aT[64][40];
    const int tid  = threadIdx.x;
    const int lane = tid & 63;
    const int wv   = tid >> 6;
    const int wn   = wv & 1, wo = wv >> 1;
    const int l15  = lane & 15, l4 = lane >> 4;
    const int g0 = blockIdx.x * 64;
    const int b  = g0 / NPIX;
    const int n0 = g0 % NPIX;
    const int o0 = blockIdx.y * 64;
    const bf16* ab = ain + (size_t)b * CCH * NPIX;

    f32x4 acc[2][2] = {};
    for (int kc = 0; kc < 8; ++kc) {
        const int c0 = kc * 32;
        for (int r = 0; r < 8; ++r) {
            int idx = r * 256 + tid;
            int ci = idx >> 6, n = idx & 63;
            aT[n][ci] = ab[(size_t)(c0 + ci) * NPIX + n0 + n];
        }
        __syncthreads();
        bf16x8 afr[2], bfr[2];
        for (int at = 0; at < 2; ++at) {
            const float* wp = w + (size_t)(o0 + wo * 32 + at * 16 + l15) * CCH + c0 + l4 * 8;
            f32x4 w0 = *(const f32x4*)wp;
            f32x4 w1 = *(const f32x4*)(wp + 4);
            bf16x8 a;
            for (int i = 0; i < 4; ++i) { a[i] = (bf16)w0[i]; a[i + 4] = (bf16)w1[i]; }
            afr[at] = a;
        }
        for (int bt = 0; bt < 2; ++bt)
            bfr[bt] = *(const bf16x8*)&aT[wn * 32 + bt * 16 + l15][l4 * 8];
        for (int at = 0; at < 2; ++at)
            for (int bt = 0; bt < 2; ++bt)
                acc[at][bt] = __builtin_amdgcn_mfma_f32_16x16x32_bf16(afr[at], bfr[bt],
                                                                     acc[at][bt], 0, 0, 0);
        __syncthreads();
    }
    for (int at = 0; at < 2; ++at)
        for (int bt = 0; bt < 2; ++bt) {
            const int n = n0 + wn * 32 + bt * 16 + l15;
            for (int r = 0; r < 4; ++r) {
                const int o = o0 + wo * 32 + at * 16 + l4 * 4 + r;
                out[(size_t)(b * 256 + o) * NPIX + n] = acc[at][bt][r] + bp[o];
            }
        }
}

// ---------------------------------------------------------------------------
extern "C" void kernel_launch(void* const* d_in, const int* in_sizes, int n_in,
                              void* d_out, int out_size, void* d_ws, size_t ws_size,
                              hipStream_t stream) {
    const float* x      = (const float*)d_in[0];
    const float* w_qkv  = (const float*)d_in[1];
    const float* w_lepe = (const float*)d_in[2];
    const float* b_lepe = (const float*)d_in[3];
    const float* w_proj = (const float*)d_in[4];
    const float* b_proj = (const float*)d_in[5];
    float* out = (float*)d_out;

    // ws layout: Qt|Kt|V|aout (bf16, 4 x 1179648 elems = 9.44MB),
    // then Opart fp32 (2*16*2304*32 = 9.44MB), MLpart fp32 (0.59MB)
    bf16* Qt   = (bf16*)d_ws;
    bf16* Kt   = Qt + 1179648;
    bf16* Vb   = Kt + 1179648;
    bf16* aout = Vb + 1179648;
    float* Opart  = (float*)((char*)d_ws + 9437184);
    float* MLpart = Opart + 2359296;

    qkv_gemm     <<<dim3(72, 12),   256, 0, stream>>>(x, w_qkv, Qt, Kt, Vb);
    attn_kernel  <<<dim3(36, 16, 2), 256, 0, stream>>>(Qt, Kt, Vb, Opart, MLpart);
    combine_kernel<<<dim3(36, 16),  256, 0, stream>>>(Opart, MLpart, aout);
    lepe_kernel  <<<dim3(512),      256, 0, stream>>>(Vb, w_lepe, b_lepe, aout);
    proj_gemm    <<<dim3(72, 4),    256, 0, stream>>>(aout, w_proj, b_proj, out);
}